// Round 8
// baseline (884.255 us; speedup 1.0000x reference)
//
#include <hip/hip_runtime.h>

#define RR 8
#define DF 128
#define SCAN_B 1024
#define CH 12800        // node chunk for M buffer (divisible by 16)

typedef __attribute__((ext_vector_type(4))) float f32x4;
typedef __attribute__((ext_vector_type(8))) short sv8;
typedef sv8 __attribute__((may_alias)) sv8a;

__device__ __forceinline__ unsigned short bf16r(float f) {
    uint32_t u = __float_as_uint(f);
    u += 0x7fffu + ((u >> 16) & 1u);   // round-to-nearest-even
    return (unsigned short)(u >> 16);
}
__device__ __forceinline__ uint32_t packbf(float lo, float hi) {
    return (uint32_t)bf16r(lo) | ((uint32_t)bf16r(hi) << 16);
}

// ---------------- CSR build (proven) ----------------
__global__ void count_kernel(const int* __restrict__ tgt, const int* __restrict__ et,
                             int* __restrict__ cnt, int E) {
    int e = blockIdx.x * blockDim.x + threadIdx.x;
    if (e < E) atomicAdd(&cnt[tgt[e] * RR + et[e]], 1);
}

__global__ void scan_local(const int* __restrict__ in, int* __restrict__ excl,
                           int* __restrict__ bsum, int n) {
    __shared__ int sm[2][SCAN_B];
    int base = blockIdx.x * SCAN_B;
    for (int t = threadIdx.x; t < SCAN_B; t += 256) {
        int idx = base + t;
        sm[0][t] = (idx < n) ? in[idx] : 0;
    }
    __syncthreads();
    int pin = 0;
    for (int off = 1; off < SCAN_B; off <<= 1) {
        for (int t = threadIdx.x; t < SCAN_B; t += 256) {
            int v = sm[pin][t];
            if (t >= off) v += sm[pin][t - off];
            sm[pin ^ 1][t] = v;
        }
        __syncthreads();
        pin ^= 1;
    }
    for (int t = threadIdx.x; t < SCAN_B; t += 256) {
        int idx = base + t;
        if (idx < n) excl[idx] = sm[pin][t] - in[idx];
    }
    if (threadIdx.x == 0) bsum[blockIdx.x] = sm[pin][SCAN_B - 1];
}

__global__ void scan_bsum(int* __restrict__ bsum, int nb) {
    __shared__ int sm[512];
    for (int t = threadIdx.x; t < nb; t += 256) sm[t] = bsum[t];
    __syncthreads();
    if (threadIdx.x == 0) {
        int run = 0;
        for (int i = 0; i < nb; ++i) { int v = sm[i]; sm[i] = run; run += v; }
    }
    __syncthreads();
    for (int t = threadIdx.x; t < nb; t += 256) bsum[t] = sm[t];
}

__global__ void scan_finish(int* __restrict__ rowptr, const int* __restrict__ bsum,
                            int* __restrict__ cursor, int n, int E) {
    int i = blockIdx.x * blockDim.x + threadIdx.x;
    if (i < n) {
        int v = rowptr[i] + bsum[i / SCAN_B];
        rowptr[i] = v;
        cursor[i] = v;
    }
    if (i == 0) rowptr[n] = E;
}

__global__ void fill_kernel(const int* __restrict__ src, const int* __restrict__ tgt,
                            const int* __restrict__ et, int* __restrict__ cursor,
                            int* __restrict__ es, int E) {
    int e = blockIdx.x * blockDim.x + threadIdx.x;
    if (e < E) {
        int seg = tgt[e] * RR + et[e];
        int pos = atomicAdd(&cursor[seg], 1);
        es[pos] = src[e];
    }
}

// ---------------- W packing into MFMA B-fragment order (proven) ----------------
__global__ void pack_w_kernel(const float* __restrict__ W, const float* __restrict__ root,
                              unsigned short* __restrict__ wp, int NT) {
    int tid = blockIdx.x * blockDim.x + threadIdx.x;
    int total = 9 * NT * 2048;
    if (tid >= total) return;
    int i = tid & 7;
    int lane = (tid >> 3) & 63;
    int kk = (tid >> 9) & 3;
    int t = (tid >> 11) % NT;
    int rel = (tid >> 11) / NT;
    int k = kk * 32 + ((lane >> 4) << 3) + i;
    int col = t * 16 + (lane & 15);
    int dout = NT * 16;
    float v = (rel < RR) ? W[((long)rel * DF + k) * dout + col] : root[(long)k * dout + col];
    wp[tid] = bf16r(v);
}

// ---------------- Phase A: max-occupancy gather-mean ----------------
// One wave per (node, rel) segment, grid-stride; rel==8 = root copy.
// One coalesced es load per 64-edge chunk (ids held lane-wise, broadcast via
// __shfl); full 512B row loads (lane = float2 feature slot). Output: mean in
// bf16 pairs, M[(local_node*9 + rel)*64 + lane]. Tiny VGPR, no LDS ->
// 8 waves/SIMD resident to hide in-order VMEM return latency.
__global__ __launch_bounds__(256) void gather_mean_kernel(
    const float* __restrict__ x,       // [N,128] f32
    const int* __restrict__ es,
    const int* __restrict__ rowptr,    // [N*8+1]
    uint32_t* __restrict__ M,          // [nn*9, 64]
    int n0, int nn) {
    const int lane = threadIdx.x & 63;
    const int wid = (blockIdx.x * 256 + threadIdx.x) >> 6;
    const int nw = (gridDim.x * 256) >> 6;
    const float2* x2 = (const float2*)x;
    const int total = nn * 9;
    for (int sid = wid; sid < total; sid += nw) {
        int loc = sid / 9;
        int rel = sid - loc * 9;
        int node = n0 + loc;
        uint32_t outv;
        if (rel == 8) {
            float2 v = x2[(long)node * 64 + lane];
            outv = packbf(v.x, v.y);
        } else {
            int seg = node * RR + rel;
            int e0 = rowptr[seg], e1 = rowptr[seg + 1];
            int cnt = e1 - e0;
            float sx = 0.f, sy = 0.f;
            for (int base = 0; base < cnt; base += 64) {
                int rem = cnt - base; rem = (rem > 64) ? 64 : rem;
                int ids = es[e0 + base + ((lane < rem) ? lane : (rem - 1))];
                int i = 0;
                for (; i + 4 <= rem; i += 4) {
                    int s0 = __shfl(ids, i), s1 = __shfl(ids, i + 1);
                    int s2 = __shfl(ids, i + 2), s3 = __shfl(ids, i + 3);
                    float2 a = x2[(long)s0 * 64 + lane];
                    float2 b = x2[(long)s1 * 64 + lane];
                    float2 c = x2[(long)s2 * 64 + lane];
                    float2 d = x2[(long)s3 * 64 + lane];
                    sx += a.x + b.x + c.x + d.x;
                    sy += a.y + b.y + c.y + d.y;
                }
                for (; i < rem; ++i) {
                    int s = __shfl(ids, i);
                    float2 a = x2[(long)s * 64 + lane];
                    sx += a.x; sy += a.y;
                }
            }
            float inv = 1.f / fmaxf((float)cnt, 1.f);
            outv = packbf(sx * inv, sy * inv);
        }
        M[(long)sid * 64 + lane] = outv;
    }
}

// ---------------- Phase B: pure MFMA transform ----------------
// 16 nodes per wave (full 16x16 A tiles, no zero rows). A-fragments loaded
// DIRECTLY from M (16B/lane), B-fragments from packed wp (proven layout),
// proven C/D mapping extended to all 64 lanes. No LDS, no barriers.
template <int NT, bool RELU>
__global__ __launch_bounds__(256) void gemm_kernel(
    const uint32_t* __restrict__ M,        // [nn*9, 64] bf16 pairs
    const unsigned short* __restrict__ wp, // packed W frags
    const float* __restrict__ bias,        // [NT*16]
    float* __restrict__ out, int n0, int nn) {
    const int wave = threadIdx.x >> 6;
    const int lane = threadIdx.x & 63;
    const int lb = (blockIdx.x * 4 + wave) * 16;   // local node base
    if (lb >= nn) return;
    const int arow = lane & 15;
    const int ag = lane >> 4;

    f32x4 acc[NT];
#pragma unroll
    for (int t = 0; t < NT; ++t) acc[t] = (f32x4){0.f, 0.f, 0.f, 0.f};

    const uint32_t* mrow = M + (long)(lb + arow) * 9 * 64 + ag * 4;

    for (int rel = 0; rel < 9; ++rel) {
        sv8 af[4];   // lane: A[arow][kk*32 + ag*8 .. +7] == 16B at kk*16 u32
#pragma unroll
        for (int kk = 0; kk < 4; ++kk)
            af[kk] = *(const sv8a*)(mrow + rel * 64 + kk * 16);
        const unsigned short* wr = wp + ((long)rel * NT << 11);
#pragma unroll
        for (int t = 0; t < NT; ++t) {
#pragma unroll
            for (int kk = 0; kk < 4; ++kk) {
                sv8 bf = *(const sv8a*)(wr + (((t * 4 + kk) << 9) + (lane << 3)));
                acc[t] = __builtin_amdgcn_mfma_f32_16x16x32_bf16(af[kk], bf, acc[t], 0, 0, 0);
            }
        }
    }

    // epilogue: C/D map col=lane&15, row=4*(lane>>4)+reg  (rows 0..15 all real)
    constexpr int DOUT = NT * 16;
#pragma unroll
    for (int t = 0; t < NT; ++t) {
        int col = t * 16 + arow;
        float bv = bias[col];
#pragma unroll
        for (int reg = 0; reg < 4; ++reg) {
            int row = ag * 4 + reg;
            float v = acc[t][reg] + bv;
            if (RELU) v = fmaxf(v, 0.f);
            out[(long)(n0 + lb + row) * DOUT + col] = v;
        }
    }
}

extern "C" void kernel_launch(void* const* d_in, const int* in_sizes, int n_in,
                              void* d_out, int out_size, void* d_ws, size_t ws_size,
                              hipStream_t stream) {
    const float* xf = (const float*)d_in[0];
    const float* W1 = (const float*)d_in[1];
    const float* r1 = (const float*)d_in[2];
    const float* b1 = (const float*)d_in[3];
    const float* W2 = (const float*)d_in[4];
    const float* r2 = (const float*)d_in[5];
    const float* b2 = (const float*)d_in[6];
    const int* eidx = (const int*)d_in[7];
    const int* etyp = (const int*)d_in[8];
    const int N = in_sizes[0] / DF;
    const int E = in_sizes[8];
    const int* src = eidx;
    const int* tgt = eidx + E;
    const int NR = N * RR;

    // ws: cnt[NR] rowptr[NR+16] cursor[NR+16] bsum[512] es[E]
    //     x1f[N*128]f32  M[CH*9*64]u32  wp1 wp2      (~66 MB total)
    int* cnt = (int*)d_ws;
    int* rowptr = cnt + NR;
    int* cursor = rowptr + NR + 16;
    int* bsum = cursor + NR + 16;
    int* es = bsum + 512;
    float* x1f = (float*)(es + E);
    uint32_t* M = (uint32_t*)(x1f + (size_t)N * DF);
    unsigned short* wp1 = (unsigned short*)(M + (size_t)CH * 9 * 64);
    unsigned short* wp2 = wp1 + 9 * 8 * 2048;

    const int nb1 = (NR + SCAN_B - 1) / SCAN_B;

    hipMemsetAsync(cnt, 0, (size_t)NR * sizeof(int), stream);
    count_kernel<<<(E + 255) / 256, 256, 0, stream>>>(tgt, etyp, cnt, E);
    scan_local<<<nb1, 256, 0, stream>>>(cnt, rowptr, bsum, NR);
    scan_bsum<<<1, 256, 0, stream>>>(bsum, nb1);
    scan_finish<<<(NR + 255) / 256, 256, 0, stream>>>(rowptr, bsum, cursor, NR, E);
    fill_kernel<<<(E + 255) / 256, 256, 0, stream>>>(src, tgt, etyp, cursor, es, E);

    pack_w_kernel<<<(9 * 8 * 2048 + 255) / 256, 256, 0, stream>>>(W1, r1, wp1, 8);
    pack_w_kernel<<<(9 * 4 * 2048 + 255) / 256, 256, 0, stream>>>(W2, r2, wp2, 4);

    const int GA = 2048;   // gather grid: 8192 waves resident
    // ---- layer 1 ----
    for (int n0 = 0; n0 < N; n0 += CH) {
        int nn = (N - n0 < CH) ? (N - n0) : CH;
        gather_mean_kernel<<<GA, 256, 0, stream>>>(xf, es, rowptr, M, n0, nn);
        gemm_kernel<8, true><<<(nn / 16 + 3) / 4, 256, 0, stream>>>(
            M, wp1, b1, x1f, n0, nn);
    }
    // ---- layer 2 ----
    for (int n0 = 0; n0 < N; n0 += CH) {
        int nn = (N - n0 < CH) ? (N - n0) : CH;
        gather_mean_kernel<<<GA, 256, 0, stream>>>(x1f, es, rowptr, M, n0, nn);
        gemm_kernel<4, false><<<(nn / 16 + 3) / 4, 256, 0, stream>>>(
            M, wp2, b2, (float*)d_out, n0, nn);
    }
}

// Round 9
// 840.239 us; speedup vs baseline: 1.0524x; 1.0524x over previous
//
#include <hip/hip_runtime.h>

#define RR 8
#define DF 128
#define SCAN_B 1024

typedef __attribute__((ext_vector_type(4))) float f32x4;
typedef __attribute__((ext_vector_type(8))) short sv8;
typedef sv8 __attribute__((may_alias)) sv8a;

__device__ __forceinline__ unsigned short bf16r(float f) {
    uint32_t u = __float_as_uint(f);
    u += 0x7fffu + ((u >> 16) & 1u);   // round-to-nearest-even
    return (unsigned short)(u >> 16);
}
__device__ __forceinline__ uint32_t packbf(float lo, float hi) {
    return (uint32_t)bf16r(lo) | ((uint32_t)bf16r(hi) << 16);
}

// ---------------- CSR build (proven) ----------------
__global__ void count_kernel(const int* __restrict__ tgt, const int* __restrict__ et,
                             int* __restrict__ cnt, int E) {
    int e = blockIdx.x * blockDim.x + threadIdx.x;
    if (e < E) atomicAdd(&cnt[tgt[e] * RR + et[e]], 1);
}

__global__ void scan_local(const int* __restrict__ in, int* __restrict__ excl,
                           int* __restrict__ bsum, int n) {
    __shared__ int sm[2][SCAN_B];
    int base = blockIdx.x * SCAN_B;
    for (int t = threadIdx.x; t < SCAN_B; t += 256) {
        int idx = base + t;
        sm[0][t] = (idx < n) ? in[idx] : 0;
    }
    __syncthreads();
    int pin = 0;
    for (int off = 1; off < SCAN_B; off <<= 1) {
        for (int t = threadIdx.x; t < SCAN_B; t += 256) {
            int v = sm[pin][t];
            if (t >= off) v += sm[pin][t - off];
            sm[pin ^ 1][t] = v;
        }
        __syncthreads();
        pin ^= 1;
    }
    for (int t = threadIdx.x; t < SCAN_B; t += 256) {
        int idx = base + t;
        if (idx < n) excl[idx] = sm[pin][t] - in[idx];
    }
    if (threadIdx.x == 0) bsum[blockIdx.x] = sm[pin][SCAN_B - 1];
}

__global__ void scan_bsum(int* __restrict__ bsum, int nb) {
    __shared__ int sm[512];
    for (int t = threadIdx.x; t < nb; t += 256) sm[t] = bsum[t];
    __syncthreads();
    if (threadIdx.x == 0) {
        int run = 0;
        for (int i = 0; i < nb; ++i) { int v = sm[i]; sm[i] = run; run += v; }
    }
    __syncthreads();
    for (int t = threadIdx.x; t < nb; t += 256) bsum[t] = sm[t];
}

__global__ void scan_finish(int* __restrict__ rowptr, const int* __restrict__ bsum,
                            int* __restrict__ cursor, int n, int E) {
    int i = blockIdx.x * blockDim.x + threadIdx.x;
    if (i < n) {
        int v = rowptr[i] + bsum[i / SCAN_B];
        rowptr[i] = v;
        cursor[i] = v;
    }
    if (i == 0) rowptr[n] = E;
}

__global__ void fill_kernel(const int* __restrict__ src, const int* __restrict__ tgt,
                            const int* __restrict__ et, int* __restrict__ cursor,
                            int* __restrict__ es, int E) {
    int e = blockIdx.x * blockDim.x + threadIdx.x;
    if (e < E) {
        int seg = tgt[e] * RR + et[e];
        int pos = atomicAdd(&cursor[seg], 1);
        es[pos] = src[e];
    }
}

// ---------------- f32 [n,2t] -> bf16-pair u32 [n,t] ----------------
__global__ void pack_x_kernel(const float* __restrict__ x, uint32_t* __restrict__ xb,
                              int n64) {
    int t = blockIdx.x * blockDim.x + threadIdx.x;
    if (t < n64) xb[t] = packbf(x[2 * t], x[2 * t + 1]);
}

// ---------------- W packing into MFMA B-fragment order (proven) ----------------
__global__ void pack_w_kernel(const float* __restrict__ W, const float* __restrict__ root,
                              unsigned short* __restrict__ wp, int NT) {
    int tid = blockIdx.x * blockDim.x + threadIdx.x;
    int total = 9 * NT * 2048;
    if (tid >= total) return;
    int i = tid & 7;
    int lane = (tid >> 3) & 63;
    int kk = (tid >> 9) & 3;
    int t = (tid >> 11) % NT;
    int rel = (tid >> 11) / NT;
    int k = kk * 32 + ((lane >> 4) << 3) + i;
    int col = t * 16 + (lane & 15);
    int dout = NT * 16;
    float v = (rel < RR) ? W[((long)rel * DF + k) * dout + col] : root[(long)k * dout + col];
    wp[tid] = bf16r(v);
}

// ---------------- Phase A: max-occupancy gather-mean, bf16 source ----------------
// One wave per (node, rel) segment, grid-stride; rel==8 = root copy. One
// coalesced es load per 64-edge chunk (ids lane-held, __shfl broadcast);
// 256B bf16 row loads (lane = u32 pair slot), f32 accumulate, bf16 M out.
// Tiny VGPR, no LDS -> ~8 waves/SIMD.
__global__ __launch_bounds__(256) void gather_mean_kernel(
    const uint32_t* __restrict__ xb,   // [N,64] bf16 pairs
    const int* __restrict__ es,
    const int* __restrict__ rowptr,    // [N*8+1]
    uint32_t* __restrict__ M,          // [nn*9, 64]
    int n0, int nn) {
    const int lane = threadIdx.x & 63;
    const int wid = (blockIdx.x * 256 + threadIdx.x) >> 6;
    const int nw = (gridDim.x * 256) >> 6;
    const int total = nn * 9;
    for (int sid = wid; sid < total; sid += nw) {
        int loc = sid / 9;
        int rel = sid - loc * 9;
        int node = n0 + loc;
        uint32_t outv;
        if (rel == 8) {
            outv = xb[(long)node * 64 + lane];
        } else {
            int seg = node * RR + rel;
            int e0 = rowptr[seg], e1 = rowptr[seg + 1];
            int cnt = e1 - e0;
            float sx = 0.f, sy = 0.f;
            for (int base = 0; base < cnt; base += 64) {
                int rem = cnt - base; rem = (rem > 64) ? 64 : rem;
                int ids = es[e0 + base + ((lane < rem) ? lane : (rem - 1))];
                int i = 0;
                for (; i + 4 <= rem; i += 4) {
                    int s0 = __shfl(ids, i), s1 = __shfl(ids, i + 1);
                    int s2 = __shfl(ids, i + 2), s3 = __shfl(ids, i + 3);
                    uint32_t a = xb[(long)s0 * 64 + lane];
                    uint32_t b = xb[(long)s1 * 64 + lane];
                    uint32_t c = xb[(long)s2 * 64 + lane];
                    uint32_t d = xb[(long)s3 * 64 + lane];
                    sx += __uint_as_float(a << 16) + __uint_as_float(b << 16) +
                          __uint_as_float(c << 16) + __uint_as_float(d << 16);
                    sy += __uint_as_float(a & 0xffff0000u) + __uint_as_float(b & 0xffff0000u) +
                          __uint_as_float(c & 0xffff0000u) + __uint_as_float(d & 0xffff0000u);
                }
                for (; i < rem; ++i) {
                    int s = __shfl(ids, i);
                    uint32_t a = xb[(long)s * 64 + lane];
                    sx += __uint_as_float(a << 16);
                    sy += __uint_as_float(a & 0xffff0000u);
                }
            }
            float inv = 1.f / fmaxf((float)cnt, 1.f);
            outv = packbf(sx * inv, sy * inv);
        }
        M[(long)sid * 64 + lane] = outv;
    }
}

// ---------------- Phase B: pure MFMA transform (proven r8) ----------------
template <int NT, bool RELU>
__global__ __launch_bounds__(256) void gemm_kernel(
    const uint32_t* __restrict__ M,        // [nn*9, 64] bf16 pairs
    const unsigned short* __restrict__ wp, // packed W frags
    const float* __restrict__ bias,        // [NT*16]
    float* __restrict__ out, int n0, int nn) {
    const int wave = threadIdx.x >> 6;
    const int lane = threadIdx.x & 63;
    const int lb = (blockIdx.x * 4 + wave) * 16;   // local node base
    if (lb >= nn) return;
    const int arow = lane & 15;
    const int ag = lane >> 4;

    f32x4 acc[NT];
#pragma unroll
    for (int t = 0; t < NT; ++t) acc[t] = (f32x4){0.f, 0.f, 0.f, 0.f};

    const uint32_t* mrow = M + (long)(lb + arow) * 9 * 64 + ag * 4;

    for (int rel = 0; rel < 9; ++rel) {
        sv8 af[4];   // lane: A[arow][kk*32 + ag*8 .. +7] == 16B at kk*16 u32
#pragma unroll
        for (int kk = 0; kk < 4; ++kk)
            af[kk] = *(const sv8a*)(mrow + rel * 64 + kk * 16);
        const unsigned short* wr = wp + ((long)rel * NT << 11);
#pragma unroll
        for (int t = 0; t < NT; ++t) {
#pragma unroll
            for (int kk = 0; kk < 4; ++kk) {
                sv8 bf = *(const sv8a*)(wr + (((t * 4 + kk) << 9) + (lane << 3)));
                acc[t] = __builtin_amdgcn_mfma_f32_16x16x32_bf16(af[kk], bf, acc[t], 0, 0, 0);
            }
        }
    }

    // epilogue: C/D map col=lane&15, row=4*(lane>>4)+reg (all 16 rows real)
    constexpr int DOUT = NT * 16;
#pragma unroll
    for (int t = 0; t < NT; ++t) {
        int col = t * 16 + arow;
        float bv = bias[col];
#pragma unroll
        for (int reg = 0; reg < 4; ++reg) {
            int row = ag * 4 + reg;
            float v = acc[t][reg] + bv;
            if (RELU) v = fmaxf(v, 0.f);
            out[(long)(n0 + lb + row) * DOUT + col] = v;
        }
    }
}

extern "C" void kernel_launch(void* const* d_in, const int* in_sizes, int n_in,
                              void* d_out, int out_size, void* d_ws, size_t ws_size,
                              hipStream_t stream) {
    const float* xf = (const float*)d_in[0];
    const float* W1 = (const float*)d_in[1];
    const float* r1 = (const float*)d_in[2];
    const float* b1 = (const float*)d_in[3];
    const float* W2 = (const float*)d_in[4];
    const float* r2 = (const float*)d_in[5];
    const float* b2 = (const float*)d_in[6];
    const int* eidx = (const int*)d_in[7];
    const int* etyp = (const int*)d_in[8];
    const int N = in_sizes[0] / DF;
    const int E = in_sizes[8];
    const int* src = eidx;
    const int* tgt = eidx + E;
    const int NR = N * RR;

    // ws layout (sequential): cnt[NR] rowptr[NR+16] cursor[NR+16] bsum[512]
    //   es[E] x1f[N*128]f32 xb[N*64]u32 x1b[N*64]u32 wp1 wp2 M[CH*9*64]u32
    int* cnt = (int*)d_ws;
    int* rowptr = cnt + NR;
    int* cursor = rowptr + NR + 16;
    int* bsum = cursor + NR + 16;
    int* es = bsum + 512;
    float* x1f = (float*)(es + E);
    uint32_t* xb = (uint32_t*)(x1f + (size_t)N * DF);
    uint32_t* x1b = xb + (size_t)N * 64;
    unsigned short* wp1 = (unsigned short*)(x1b + (size_t)N * 64);
    unsigned short* wp2 = wp1 + 9 * 8 * 2048;
    uint32_t* M = (uint32_t*)(wp2 + 9 * 4 * 2048);

    size_t used = (size_t)((char*)M - (char*)d_ws);
    size_t avail = (ws_size > used) ? (ws_size - used) : 0;
    int CH = (int)(avail / (9 * 64 * sizeof(uint32_t)));
    CH &= ~63;                       // multiple of 64 (=> chunk mult of 16)
    if (CH > N) CH = ((N + 63) / 64) * 64;
    if (CH > 12800) CH = 12800;      // diminishing returns; keeps M <= 29.5 MB
    if (CH < 64) CH = 64;            // degenerate fallback

    const int nb1 = (NR + SCAN_B - 1) / SCAN_B;

    hipMemsetAsync(cnt, 0, (size_t)NR * sizeof(int), stream);
    count_kernel<<<(E + 255) / 256, 256, 0, stream>>>(tgt, etyp, cnt, E);
    scan_local<<<nb1, 256, 0, stream>>>(cnt, rowptr, bsum, NR);
    scan_bsum<<<1, 256, 0, stream>>>(bsum, nb1);
    scan_finish<<<(NR + 255) / 256, 256, 0, stream>>>(rowptr, bsum, cursor, NR, E);
    fill_kernel<<<(E + 255) / 256, 256, 0, stream>>>(src, tgt, etyp, cursor, es, E);

    pack_x_kernel<<<(N * 64 + 255) / 256, 256, 0, stream>>>(xf, xb, N * 64);
    pack_w_kernel<<<(9 * 8 * 2048 + 255) / 256, 256, 0, stream>>>(W1, r1, wp1, 8);
    pack_w_kernel<<<(9 * 4 * 2048 + 255) / 256, 256, 0, stream>>>(W2, r2, wp2, 4);

    const int GA = 2048;   // 8192 waves resident
    // ---- layer 1 ----
    for (int n0 = 0; n0 < N; n0 += CH) {
        int nn = (N - n0 < CH) ? (N - n0) : CH;
        gather_mean_kernel<<<GA, 256, 0, stream>>>(xb, es, rowptr, M, n0, nn);
        gemm_kernel<8, true><<<((nn + 15) / 16 + 3) / 4, 256, 0, stream>>>(
            M, wp1, b1, x1f, n0, nn);
    }
    pack_x_kernel<<<(N * 64 + 255) / 256, 256, 0, stream>>>(x1f, x1b, N * 64);
    // ---- layer 2 ----
    for (int n0 = 0; n0 < N; n0 += CH) {
        int nn = (N - n0 < CH) ? (N - n0) : CH;
        gather_mean_kernel<<<GA, 256, 0, stream>>>(x1b, es, rowptr, M, n0, nn);
        gemm_kernel<4, false><<<((nn + 15) / 16 + 3) / 4, 256, 0, stream>>>(
            M, wp2, b2, (float*)d_out, n0, nn);
    }
}